// Round 1
// baseline (1031.874 us; speedup 1.0000x reference)
//
#include <hip/hip_runtime.h>
#include <hip/hip_bf16.h>
#include <math.h>

#define EMB 768
#define HEADS 12
#define DKH 64
#define DFF 3072
#define NB 16
#define SEQ 577
#define MTOK (NB*SEQ)      // 9232
#define BHN (NB*HEADS)     // 192
#define PLD 584            // padded row stride (bf16 elems) for P and vT, 16B-aligned
#define CB 16              // heads (b,h) per attention chunk

typedef __attribute__((ext_vector_type(8))) short short8;
typedef __attribute__((ext_vector_type(4))) float f32x4;

union U8 { unsigned short s[8]; uint4 v; };

__device__ __forceinline__ unsigned short f2bf(float f) {
  __hip_bfloat16 h = __float2bfloat16(f);
  return *reinterpret_cast<unsigned short*>(&h);
}

// ---------------- LayerNorm: fp32 [row,768] -> bf16 [row,768] ----------------
__global__ __launch_bounds__(256) void ln_kernel(
    const float* __restrict__ x, const float* __restrict__ g,
    const float* __restrict__ b, unsigned short* __restrict__ out) {
  int row = blockIdx.x;
  int tid = threadIdx.x;
  const float* xr = x + (long)row * EMB;
  float v0 = xr[tid], v1 = xr[tid + 256], v2 = xr[tid + 512];
  float s = v0 + v1 + v2;
  float sq = v0*v0 + v1*v1 + v2*v2;
  for (int off = 32; off; off >>= 1) {
    s  += __shfl_down(s,  off, 64);
    sq += __shfl_down(sq, off, 64);
  }
  __shared__ float sh[8];
  int wid = tid >> 6, lane = tid & 63;
  if (lane == 0) { sh[wid] = s; sh[4 + wid] = sq; }
  __syncthreads();
  s  = sh[0] + sh[1] + sh[2] + sh[3];
  sq = sh[4] + sh[5] + sh[6] + sh[7];
  float mu = s * (1.0f / EMB);
  float var = sq * (1.0f / EMB) - mu * mu;
  float rs = rsqrtf(var + 1e-5f);
  unsigned short* orow = out + (long)row * EMB;
  orow[tid]       = f2bf((v0 - mu) * rs * g[tid]       + b[tid]);
  orow[tid + 256] = f2bf((v1 - mu) * rs * g[tid + 256] + b[tid + 256]);
  orow[tid + 512] = f2bf((v2 - mu) * rs * g[tid + 512] + b[tid + 512]);
}

// ------------- transpose+convert: fp32 src[R,C] -> bf16 dst[C,R] -------------
__global__ __launch_bounds__(256) void transpose_convert(
    const float* __restrict__ src, unsigned short* __restrict__ dst,
    int R, int C) {
  __shared__ float t[32][33];
  int tx = threadIdx.x & 31, ty = threadIdx.x >> 5;
  int r0 = blockIdx.y * 32, c0 = blockIdx.x * 32;
#pragma unroll
  for (int l = 0; l < 4; l++)
    t[ty + l*8][tx] = src[(long)(r0 + ty + l*8) * C + c0 + tx];
  __syncthreads();
#pragma unroll
  for (int l = 0; l < 4; l++)
    dst[(long)(c0 + ty + l*8) * R + r0 + tx] = f2bf(t[tx][ty + l*8]);
}

// ------------------- concat bq|bk|bv into one fp32[2304] ---------------------
__global__ void concat_bias(const float* __restrict__ a, const float* __restrict__ b,
                            const float* __restrict__ c, float* __restrict__ o) {
  int i = blockIdx.x * 256 + threadIdx.x;
  if (i < 768) o[i] = a[i];
  else if (i < 1536) o[i] = b[i - 768];
  else if (i < 2304) o[i] = c[i - 1536];
}

// --------- vT: qkv v-part [b,s,h,d] -> vT[bh][d][s] (row stride PLD) ---------
__global__ __launch_bounds__(256) void transpose_v(
    const unsigned short* __restrict__ qkv, unsigned short* __restrict__ vT) {
  __shared__ unsigned short t[32][33];
  int bhi = blockIdx.z;
  int b = bhi / HEADS, h = bhi % HEADS;
  int s0 = blockIdx.x * 32, d0 = blockIdx.y * 32;
  int tx = threadIdx.x & 31, ty = threadIdx.x >> 5;
  const unsigned short* base = qkv + ((long)b * SEQ) * (3*EMB) + 2*EMB + h*DKH;
#pragma unroll
  for (int l = 0; l < 4; l++) {
    int s = s0 + ty + l*8;
    t[ty + l*8][tx] = (s < SEQ) ? base[(long)s * (3*EMB) + d0 + tx] : (unsigned short)0;
  }
  __syncthreads();
  unsigned short* ob = vT + ((long)bhi * DKH) * PLD;
#pragma unroll
  for (int l = 0; l < 4; l++) {
    int d = d0 + ty + l*8;
    int s = s0 + tx;
    if (s < SEQ) ob[(long)d * PLD + s] = t[tx][ty + l*8];
  }
}

// --------- softmax over rows of 577 fp32; write bf16 P (stride PLD) ----------
__global__ __launch_bounds__(256) void softmax_rows(
    const float* __restrict__ scores, unsigned short* __restrict__ P) {
  int row = blockIdx.x;
  int tid = threadIdx.x;
  const float* sr = scores + (long)row * SEQ;
  int i0 = tid, i1 = tid + 256, i2 = tid + 512;
  float v0 = (i0 < SEQ) ? sr[i0] : -1e30f;
  float v1 = (i1 < SEQ) ? sr[i1] : -1e30f;
  float v2 = (i2 < SEQ) ? sr[i2] : -1e30f;
  float mx = fmaxf(fmaxf(v0, v1), v2);
  for (int off = 32; off; off >>= 1) mx = fmaxf(mx, __shfl_down(mx, off, 64));
  __shared__ float sh[4];
  int wid = tid >> 6, lane = tid & 63;
  if (lane == 0) sh[wid] = mx;
  __syncthreads();
  mx = fmaxf(fmaxf(sh[0], sh[1]), fmaxf(sh[2], sh[3]));
  __syncthreads();
  float e0 = (i0 < SEQ) ? __expf(v0 - mx) : 0.0f;
  float e1 = (i1 < SEQ) ? __expf(v1 - mx) : 0.0f;
  float e2 = (i2 < SEQ) ? __expf(v2 - mx) : 0.0f;
  float s = e0 + e1 + e2;
  for (int off = 32; off; off >>= 1) s += __shfl_down(s, off, 64);
  if (lane == 0) sh[wid] = s;
  __syncthreads();
  s = sh[0] + sh[1] + sh[2] + sh[3];
  float inv = 1.0f / s;
  unsigned short* pr = P + (long)row * PLD;
  if (i0 < SEQ) pr[i0] = f2bf(e0 * inv);
  if (i1 < SEQ) pr[i1] = f2bf(e1 * inv);
  if (i2 < SEQ) pr[i2] = f2bf(e2 * inv);
}

// ---------------- generic strided-batched bf16 GEMM: C = A @ Bt^T ------------
// A [M,K] bf16 row-major (lda), Bt [N,K] bf16 row-major (ldb).
// Batch offset modes: mode0 -> z*s1 ; mode1 -> (bh/12)*s1 + (bh%12)*s2, bh=bh0+z.
template<bool BIAS, bool RESID, bool GELU_, bool OF32>
__global__ __launch_bounds__(256) void gemm_bt(
    const unsigned short* __restrict__ A,
    const unsigned short* __restrict__ Bt,
    const float* __restrict__ bias,
    const float* __restrict__ resid,
    float* __restrict__ outf,
    unsigned short* __restrict__ outb,
    int M, int N, int K, int lda, int ldb, int ldc,
    int bh0,
    int modeA, long sA1, long sA2,
    int modeB, long sB1, long sB2,
    int modeC, long sC1, long sC2) {
  __shared__ unsigned short As[64 * 40];  // pad to 40 bf16 (80B rows, 16B aligned)
  __shared__ unsigned short Bs[64 * 40];

  const int z = blockIdx.z;
  const int bh = bh0 + z;
  const long offA = modeA ? (long)(bh / HEADS) * sA1 + (long)(bh % HEADS) * sA2 : (long)z * sA1;
  const long offB = modeB ? (long)(bh / HEADS) * sB1 + (long)(bh % HEADS) * sB2 : (long)z * sB1;
  const long offC = modeC ? (long)(bh / HEADS) * sC1 + (long)(bh % HEADS) * sC2 : (long)z * sC1;
  const unsigned short* Ab = A + offA;
  const unsigned short* Bb = Bt + offB;

  const int m0 = blockIdx.y * 64, n0 = blockIdx.x * 64;
  const int tid = threadIdx.x;
  const int wave = tid >> 6, lane = tid & 63;
  const int wm = (wave >> 1) * 32, wn = (wave & 1) * 32;
  const int lm = lane & 15, q = lane >> 4;
  const int ar = tid >> 2, ac = (tid & 3) * 8;

  f32x4 acc00 = {0,0,0,0}, acc01 = {0,0,0,0}, acc10 = {0,0,0,0}, acc11 = {0,0,0,0};

  for (int k0 = 0; k0 < K; k0 += 32) {
    U8 ua; ua.v = make_uint4(0,0,0,0);
    int gm = m0 + ar;
    if (gm < M) {
      const unsigned short* src = Ab + (long)gm * lda + k0 + ac;
      if (k0 + ac + 8 <= K) ua.v = *(const uint4*)src;
      else {
#pragma unroll
        for (int j = 0; j < 8; j++) ua.s[j] = (k0 + ac + j < K) ? src[j] : (unsigned short)0;
      }
    }
    U8 ub; ub.v = make_uint4(0,0,0,0);
    int gn = n0 + ar;
    if (gn < N) {
      const unsigned short* src = Bb + (long)gn * ldb + k0 + ac;
      if (k0 + ac + 8 <= K) ub.v = *(const uint4*)src;
      else {
#pragma unroll
        for (int j = 0; j < 8; j++) ub.s[j] = (k0 + ac + j < K) ? src[j] : (unsigned short)0;
      }
    }
    *(uint4*)&As[ar * 40 + ac] = ua.v;
    *(uint4*)&Bs[ar * 40 + ac] = ub.v;
    __syncthreads();

    short8 a0 = *(const short8*)&As[(wm + lm) * 40 + q * 8];
    short8 a1 = *(const short8*)&As[(wm + 16 + lm) * 40 + q * 8];
    short8 b0 = *(const short8*)&Bs[(wn + lm) * 40 + q * 8];
    short8 b1 = *(const short8*)&Bs[(wn + 16 + lm) * 40 + q * 8];
    acc00 = __builtin_amdgcn_mfma_f32_16x16x32_bf16(a0, b0, acc00, 0, 0, 0);
    acc01 = __builtin_amdgcn_mfma_f32_16x16x32_bf16(a0, b1, acc01, 0, 0, 0);
    acc10 = __builtin_amdgcn_mfma_f32_16x16x32_bf16(a1, b0, acc10, 0, 0, 0);
    acc11 = __builtin_amdgcn_mfma_f32_16x16x32_bf16(a1, b1, acc11, 0, 0, 0);
    __syncthreads();
  }

#pragma unroll
  for (int i = 0; i < 2; i++) {
#pragma unroll
    for (int j = 0; j < 2; j++) {
      f32x4 a = (i == 0) ? (j == 0 ? acc00 : acc01) : (j == 0 ? acc10 : acc11);
      int col = n0 + wn + j * 16 + lm;
      if (col >= N) continue;
      float bv = BIAS ? bias[col] : 0.0f;
#pragma unroll
      for (int r = 0; r < 4; r++) {
        int row = m0 + wm + i * 16 + q * 4 + r;
        if (row >= M) continue;
        float v = a[r] + bv;
        if (RESID) v += resid[(long)row * ldc + col];
        if (GELU_) v = 0.5f * v * (1.0f + erff(v * 0.70710678118654752f));
        long o = offC + (long)row * ldc + col;
        if (OF32) outf[o] = v;
        else      outb[o] = f2bf(v);
      }
    }
  }
}

extern "C" void kernel_launch(void* const* d_in, const int* in_sizes, int n_in,
                              void* d_out, int out_size, void* d_ws, size_t ws_size,
                              hipStream_t stream) {
  const float* x     = (const float*)d_in[0];
  const float* wq    = (const float*)d_in[1];
  const float* bq    = (const float*)d_in[2];
  const float* wk    = (const float*)d_in[3];
  const float* bk    = (const float*)d_in[4];
  const float* wv    = (const float*)d_in[5];
  const float* bv    = (const float*)d_in[6];
  const float* wo    = (const float*)d_in[7];
  const float* bo    = (const float*)d_in[8];
  const float* w1    = (const float*)d_in[9];
  const float* bf1   = (const float*)d_in[10];
  const float* w2    = (const float*)d_in[11];
  const float* bf2   = (const float*)d_in[12];
  const float* ln1g  = (const float*)d_in[13];
  const float* ln1b  = (const float*)d_in[14];
  const float* ln2g  = (const float*)d_in[15];
  const float* ln2b  = (const float*)d_in[16];
  float* out = (float*)d_out;

  // ---- workspace layout (256B aligned) ----
  char* w = (char*)d_ws;
  size_t off = 0;
  auto alloc = [&](size_t bytes) -> void* {
    void* p = w + off;
    off = (off + bytes + 255) & ~(size_t)255;
    return p;
  };
  unsigned short* WqkvT = (unsigned short*)alloc((size_t)3 * 768 * 768 * 2);
  unsigned short* WoT   = (unsigned short*)alloc((size_t)768 * 768 * 2);
  unsigned short* W1T   = (unsigned short*)alloc((size_t)3072 * 768 * 2);   // [3072][768]
  unsigned short* W2T   = (unsigned short*)alloc((size_t)768 * 3072 * 2);   // [768][3072]
  float*          bqkv  = (float*)alloc(2304 * 4);
  unsigned short* hbuf  = (unsigned short*)alloc((size_t)MTOK * EMB * 2);   // h1 / ctx / h2
  unsigned short* qkv   = (unsigned short*)alloc((size_t)MTOK * 3 * EMB * 2);
  unsigned short* vT    = (unsigned short*)alloc((size_t)BHN * DKH * PLD * 2);
  float*          x1    = (float*)alloc((size_t)MTOK * EMB * 4);
  // region B: scores(fp32)+P(bf16) per chunk, later reused as g (bf16)
  size_t scoresBytes = ((size_t)CB * SEQ * SEQ * 4 + 255) & ~(size_t)255;
  size_t pBytes      = (size_t)CB * SEQ * PLD * 2;
  size_t gBytes      = (size_t)MTOK * DFF * 2;
  size_t regionB     = scoresBytes + pBytes > gBytes ? scoresBytes + pBytes : gBytes;
  char* rb = (char*)alloc(regionB);
  float*          scores = (float*)rb;
  unsigned short* P      = (unsigned short*)(rb + scoresBytes);
  unsigned short* g      = (unsigned short*)rb;
  (void)ws_size; (void)in_sizes; (void)n_in; (void)out_size;

  dim3 blk(256);

  // weights -> bf16 transposed [N,K]
  transpose_convert<<<dim3(24, 24), blk, 0, stream>>>(wq, WqkvT,               768, 768);
  transpose_convert<<<dim3(24, 24), blk, 0, stream>>>(wk, WqkvT + 768 * 768,   768, 768);
  transpose_convert<<<dim3(24, 24), blk, 0, stream>>>(wv, WqkvT + 2*768*768,   768, 768);
  transpose_convert<<<dim3(24, 24), blk, 0, stream>>>(wo, WoT,                 768, 768);
  transpose_convert<<<dim3(96, 24), blk, 0, stream>>>(w1, W1T,                 768, 3072);
  transpose_convert<<<dim3(24, 96), blk, 0, stream>>>(w2, W2T,                 3072, 768);
  concat_bias<<<dim3(9), blk, 0, stream>>>(bq, bk, bv, bqkv);

  // LN1 -> hbuf (bf16)
  ln_kernel<<<dim3(MTOK), blk, 0, stream>>>(x, ln1g, ln1b, hbuf);

  // QKV: [9232,768] @ [768,2304] -> qkv bf16 [9232,2304]
  gemm_bt<true, false, false, false><<<dim3(36, 145, 1), blk, 0, stream>>>(
      hbuf, WqkvT, bqkv, nullptr, nullptr, qkv,
      MTOK, 3 * EMB, EMB, EMB, EMB, 3 * EMB,
      0, 0, 0, 0, 0, 0, 0, 0, 0, 0);

  // vT[bh][d][s]
  transpose_v<<<dim3(19, 2, BHN), blk, 0, stream>>>(qkv, vT);

  // attention in chunks of CB (b,h) pairs
  for (int c = 0; c < BHN / CB; c++) {
    int bh0 = c * CB;
    // scores = Q @ K^T  (unscaled, fp32)
    gemm_bt<false, false, false, true><<<dim3(10, 10, CB), blk, 0, stream>>>(
        qkv, qkv + EMB, nullptr, nullptr, scores, nullptr,
        SEQ, SEQ, DKH, 3 * EMB, 3 * EMB, SEQ,
        bh0,
        1, (long)SEQ * 3 * EMB, DKH,
        1, (long)SEQ * 3 * EMB, DKH,
        0, (long)SEQ * SEQ, 0);
    // softmax rows -> bf16 P
    softmax_rows<<<dim3(CB * SEQ), blk, 0, stream>>>(scores, P);
    // ctx = P @ V  -> hbuf (bf16) at [b*577+s, h*64+d]
    gemm_bt<false, false, false, false><<<dim3(1, 10, CB), blk, 0, stream>>>(
        P, vT, nullptr, nullptr, nullptr, hbuf,
        SEQ, DKH, SEQ, PLD, PLD, EMB,
        bh0,
        0, (long)SEQ * PLD, 0,
        1, (long)HEADS * DKH * PLD, (long)DKH * PLD,
        1, (long)SEQ * EMB, DKH);
  }

  // O-proj + residual -> x1 (fp32)
  gemm_bt<true, true, false, true><<<dim3(12, 145, 1), blk, 0, stream>>>(
      hbuf, WoT, bo, x, x1, nullptr,
      MTOK, EMB, EMB, EMB, EMB, EMB,
      0, 0, 0, 0, 0, 0, 0, 0, 0, 0);

  // LN2 -> hbuf (bf16)
  ln_kernel<<<dim3(MTOK), blk, 0, stream>>>(x1, ln2g, ln2b, hbuf);

  // FFN1 + bias + exact GELU -> g (bf16)
  gemm_bt<true, false, true, false><<<dim3(48, 145, 1), blk, 0, stream>>>(
      hbuf, W1T, bf1, nullptr, nullptr, g,
      MTOK, DFF, EMB, EMB, EMB, DFF,
      0, 0, 0, 0, 0, 0, 0, 0, 0, 0);

  // FFN2 + bias + residual -> out (fp32)
  gemm_bt<true, true, false, true><<<dim3(12, 145, 1), blk, 0, stream>>>(
      g, W2T, bf2, x1, out, nullptr,
      MTOK, EMB, DFF, DFF, DFF, EMB,
      0, 0, 0, 0, 0, 0, 0, 0, 0, 0);
}

// Round 2
// 543.332 us; speedup vs baseline: 1.8992x; 1.8992x over previous
//
#include <hip/hip_runtime.h>
#include <hip/hip_bf16.h>
#include <math.h>

#define EMB 768
#define HEADS 12
#define DKH 64
#define DFF 3072
#define NB 16
#define SEQ 577
#define MTOK (NB*SEQ)      // 9232
#define BHN (NB*HEADS)     // 192
#define VLD 640            // vT row stride (bf16 elems): 64-elem tiles never cross rows

typedef __attribute__((ext_vector_type(8))) short short8;
typedef __attribute__((ext_vector_type(4))) float f32x4;

__device__ __forceinline__ unsigned short f2bf(float f) {
  __hip_bfloat16 h = __float2bfloat16(f);
  return *reinterpret_cast<unsigned short*>(&h);
}

__device__ __forceinline__ void gld_lds16(const unsigned short* g, unsigned short* l) {
  __builtin_amdgcn_global_load_lds(
      (const __attribute__((address_space(1))) unsigned int*)(g),
      (__attribute__((address_space(3))) unsigned int*)(l), 16, 0, 0);
}

// ---------------- LayerNorm: fp32 [row,768] -> bf16 [row,768] ----------------
__global__ __launch_bounds__(256) void ln_kernel(
    const float* __restrict__ x, const float* __restrict__ g,
    const float* __restrict__ b, unsigned short* __restrict__ out) {
  int row = blockIdx.x;
  int tid = threadIdx.x;
  const float* xr = x + (long)row * EMB;
  float v0 = xr[tid], v1 = xr[tid + 256], v2 = xr[tid + 512];
  float s = v0 + v1 + v2;
  float sq = v0*v0 + v1*v1 + v2*v2;
  for (int off = 32; off; off >>= 1) {
    s  += __shfl_down(s,  off, 64);
    sq += __shfl_down(sq, off, 64);
  }
  __shared__ float sh[8];
  int wid = tid >> 6, lane = tid & 63;
  if (lane == 0) { sh[wid] = s; sh[4 + wid] = sq; }
  __syncthreads();
  s  = sh[0] + sh[1] + sh[2] + sh[3];
  sq = sh[4] + sh[5] + sh[6] + sh[7];
  float mu = s * (1.0f / EMB);
  float var = sq * (1.0f / EMB) - mu * mu;
  float rs = rsqrtf(var + 1e-5f);
  unsigned short* orow = out + (long)row * EMB;
  orow[tid]       = f2bf((v0 - mu) * rs * g[tid]       + b[tid]);
  orow[tid + 256] = f2bf((v1 - mu) * rs * g[tid + 256] + b[tid + 256]);
  orow[tid + 512] = f2bf((v2 - mu) * rs * g[tid + 512] + b[tid + 512]);
}

// ------------- transpose+convert: fp32 src[R,C] -> bf16 dst[C,R] -------------
__global__ __launch_bounds__(256) void transpose_convert(
    const float* __restrict__ src, unsigned short* __restrict__ dst,
    int R, int C) {
  __shared__ float t[32][33];
  int tx = threadIdx.x & 31, ty = threadIdx.x >> 5;
  int r0 = blockIdx.y * 32, c0 = blockIdx.x * 32;
#pragma unroll
  for (int l = 0; l < 4; l++)
    t[ty + l*8][tx] = src[(long)(r0 + ty + l*8) * C + c0 + tx];
  __syncthreads();
#pragma unroll
  for (int l = 0; l < 4; l++)
    dst[(long)(c0 + ty + l*8) * R + r0 + tx] = f2bf(t[tx][ty + l*8]);
}

// ------------------- concat bq|bk|bv into one fp32[2304] ---------------------
__global__ void concat_bias(const float* __restrict__ a, const float* __restrict__ b,
                            const float* __restrict__ c, float* __restrict__ o) {
  int i = blockIdx.x * 256 + threadIdx.x;
  if (i < 768) o[i] = a[i];
  else if (i < 1536) o[i] = b[i - 768];
  else if (i < 2304) o[i] = c[i - 1536];
}

// --------- vT: qkv v-part [b,s,h,d] -> vT[bh][d][s] (row stride VLD) ---------
__global__ __launch_bounds__(256) void transpose_v(
    const unsigned short* __restrict__ qkv, unsigned short* __restrict__ vT) {
  __shared__ unsigned short t[32][33];
  int bhi = blockIdx.z;
  int b = bhi / HEADS, h = bhi % HEADS;
  int s0 = blockIdx.x * 32, d0 = blockIdx.y * 32;
  int tx = threadIdx.x & 31, ty = threadIdx.x >> 5;
  const unsigned short* base = qkv + ((long)b * SEQ) * (3*EMB) + 2*EMB + h*DKH;
#pragma unroll
  for (int l = 0; l < 4; l++) {
    int s = s0 + ty + l*8;
    t[ty + l*8][tx] = (s < SEQ) ? base[(long)s * (3*EMB) + d0 + tx] : (unsigned short)0;
  }
  __syncthreads();
  unsigned short* ob = vT + ((long)bhi * DKH) * VLD;
#pragma unroll
  for (int l = 0; l < 4; l++) {
    int d = d0 + ty + l*8;
    int s = s0 + tx;
    if (s < SEQ) ob[(long)d * VLD + s] = t[tx][ty + l*8];
  }
}

// --------------- m97-structure GEMM: C[M,N] = A[M,K] @ Bt[N,K]^T -------------
// 128x128 tile, BK=32, global_load_lds width 16, 4 waves x 4x4 mfma 16x16x32.
template<bool BIAS, bool RESID, bool GELU_, bool OF32>
__global__ __launch_bounds__(256) void gemm128(
    const unsigned short* __restrict__ A,
    const unsigned short* __restrict__ Bt,
    const float* __restrict__ bias,
    const float* __restrict__ resid,
    float* __restrict__ outf,
    unsigned short* __restrict__ outb,
    int M, int N, int K, int lda, int ldb, int ldc) {
  __shared__ unsigned short As[128 * 32];  // row-major, unpadded (global_load_lds layout)
  __shared__ unsigned short Bs[128 * 32];

  const int m0 = blockIdx.y * 128, n0 = blockIdx.x * 128;
  const int tid = threadIdx.x;
  const int wave = tid >> 6, lane = tid & 63;
  const int wm = (wave >> 1) * 64, wn = (wave & 1) * 64;
  const int lm = lane & 15, q = lane >> 4;

  // staging: thread covers 8 elems (16B); lds elem off = 8*tid + c*2048
  const int srow = tid >> 2;
  const int scol = (tid & 3) * 8;
  int gmA0 = m0 + srow;        if (gmA0 > M - 1) gmA0 = M - 1;
  int gmA1 = m0 + srow + 64;   if (gmA1 > M - 1) gmA1 = M - 1;
  const int gnB0 = n0 + srow, gnB1 = n0 + srow + 64;

  f32x4 acc[4][4];
#pragma unroll
  for (int i = 0; i < 4; i++)
#pragma unroll
    for (int j = 0; j < 4; j++) acc[i][j] = (f32x4){0,0,0,0};

  for (int k0 = 0; k0 < K; k0 += 32) {
    gld_lds16(A  + (long)gmA0 * lda + k0 + scol, &As[8*tid]);
    gld_lds16(A  + (long)gmA1 * lda + k0 + scol, &As[8*tid + 2048]);
    gld_lds16(Bt + (long)gnB0 * ldb + k0 + scol, &Bs[8*tid]);
    gld_lds16(Bt + (long)gnB1 * ldb + k0 + scol, &Bs[8*tid + 2048]);
    asm volatile("s_waitcnt vmcnt(0)" ::: "memory");
    __syncthreads();

    short8 af[4], bf[4];
#pragma unroll
    for (int i = 0; i < 4; i++) af[i] = *(const short8*)&As[(wm + i*16 + lm) * 32 + q*8];
#pragma unroll
    for (int j = 0; j < 4; j++) bf[j] = *(const short8*)&Bs[(wn + j*16 + lm) * 32 + q*8];
#pragma unroll
    for (int i = 0; i < 4; i++)
#pragma unroll
      for (int j = 0; j < 4; j++)
        acc[i][j] = __builtin_amdgcn_mfma_f32_16x16x32_bf16(af[i], bf[j], acc[i][j], 0, 0, 0);
    __syncthreads();
  }

#pragma unroll
  for (int i = 0; i < 4; i++) {
#pragma unroll
    for (int j = 0; j < 4; j++) {
      int col = n0 + wn + j*16 + lm;
      float bv = BIAS ? bias[col] : 0.0f;
#pragma unroll
      for (int r = 0; r < 4; r++) {
        int row = m0 + wm + i*16 + q*4 + r;
        if (row >= M) continue;
        float v = acc[i][j][r] + bv;
        if (RESID) v += resid[(long)row * ldc + col];
        if (GELU_) v = 0.5f * v * (1.0f + erff(v * 0.70710678118654752f));
        long o = (long)row * ldc + col;
        if (OF32) outf[o] = v;
        else      outb[o] = f2bf(v);
      }
    }
  }
}

// ------------------ fused flash attention (unscaled scores) ------------------
// grid (10 qtiles, 192 bh). Block: 4 waves; wave w owns q rows [w*16, w*16+16).
#define FLD 72   // LDS row stride (bf16): 144B = odd multiple of 16B -> low conflict
__global__ __launch_bounds__(256) void flash_attn(
    const unsigned short* __restrict__ qkv,   // [MTOK][2304], q|k|v
    const unsigned short* __restrict__ vT,    // [bh][64][VLD]
    unsigned short* __restrict__ ctx) {       // [MTOK][768]
  __shared__ unsigned short Qs[64 * FLD];
  __shared__ unsigned short Ks[64 * FLD];
  __shared__ unsigned short Vts[64 * FLD];
  __shared__ unsigned short Ps[64 * FLD];

  const int q0 = blockIdx.x * 64;
  const int bh = blockIdx.y;
  const int b = bh / HEADS, h = bh % HEADS;
  const int tid = threadIdx.x;
  const int wave = tid >> 6, lane = tid & 63;
  const int lm = lane & 15, q = lane >> 4;

  const int sr = tid >> 3;          // 0..31 staging row
  const int sc = (tid & 7) * 8;     // 0..56 staging col

  // stage Q tile (rows clamped)
#pragma unroll
  for (int it = 0; it < 2; it++) {
    int r = sr + it*32;
    int s = q0 + r; if (s > SEQ - 1) s = SEQ - 1;
    *(uint4*)&Qs[r*FLD + sc] =
        *(const uint4*)(qkv + ((long)(b*SEQ + s))*(3*EMB) + h*DKH + sc);
  }
  __syncthreads();
  short8 qf0 = *(const short8*)&Qs[(wave*16 + lm)*FLD + q*8];
  short8 qf1 = *(const short8*)&Qs[(wave*16 + lm)*FLD + 32 + q*8];

  f32x4 oacc[4];
#pragma unroll
  for (int j = 0; j < 4; j++) oacc[j] = (f32x4){0,0,0,0};
  float mrun[4] = {-1e30f, -1e30f, -1e30f, -1e30f};
  float lrun[4] = {0.f, 0.f, 0.f, 0.f};

  for (int kt = 0; kt < 10; kt++) {
    __syncthreads();   // prev iter's K/Vt reads done
#pragma unroll
    for (int it = 0; it < 2; it++) {
      int r = sr + it*32;
      int s = kt*64 + r; if (s > SEQ - 1) s = SEQ - 1;
      *(uint4*)&Ks[r*FLD + sc] =
          *(const uint4*)(qkv + ((long)(b*SEQ + s))*(3*EMB) + EMB + h*DKH + sc);
      *(uint4*)&Vts[r*FLD + sc] =
          *(const uint4*)(vT + ((long)bh*DKH + r)*VLD + kt*64 + sc);
    }
    __syncthreads();

    // S = Q @ K^T  (16 q-rows x 64 keys per wave)
    f32x4 sacc[4];
#pragma unroll
    for (int t = 0; t < 4; t++) {
      short8 kf0 = *(const short8*)&Ks[(t*16 + lm)*FLD + q*8];
      short8 kf1 = *(const short8*)&Ks[(t*16 + lm)*FLD + 32 + q*8];
      sacc[t] = __builtin_amdgcn_mfma_f32_16x16x32_bf16(qf0, kf0, (f32x4){0,0,0,0}, 0, 0, 0);
      sacc[t] = __builtin_amdgcn_mfma_f32_16x16x32_bf16(qf1, kf1, sacc[t], 0, 0, 0);
      int key = kt*64 + t*16 + lm;
      if (key >= SEQ) sacc[t] = (f32x4){-1e30f, -1e30f, -1e30f, -1e30f};
    }

    // online softmax over this tile's 64 keys
    float mt[4];
#pragma unroll
    for (int r = 0; r < 4; r++)
      mt[r] = fmaxf(fmaxf(sacc[0][r], sacc[1][r]), fmaxf(sacc[2][r], sacc[3][r]));
#pragma unroll
    for (int d = 1; d <= 8; d <<= 1)
#pragma unroll
      for (int r = 0; r < 4; r++) mt[r] = fmaxf(mt[r], __shfl_xor(mt[r], d, 64));

    float alpha[4], rs[4];
#pragma unroll
    for (int r = 0; r < 4; r++) {
      float mnew = fmaxf(mrun[r], mt[r]);
      alpha[r] = __expf(mrun[r] - mnew);
      mrun[r] = mnew;
      rs[r] = 0.f;
    }
#pragma unroll
    for (int t = 0; t < 4; t++)
#pragma unroll
      for (int r = 0; r < 4; r++) {
        float p = __expf(sacc[t][r] - mrun[r]);
        sacc[t][r] = p;
        rs[r] += p;
      }
#pragma unroll
    for (int d = 1; d <= 8; d <<= 1)
#pragma unroll
      for (int r = 0; r < 4; r++) rs[r] += __shfl_xor(rs[r], d, 64);
#pragma unroll
    for (int r = 0; r < 4; r++) lrun[r] = alpha[r]*lrun[r] + rs[r];
#pragma unroll
    for (int j = 0; j < 4; j++)
#pragma unroll
      for (int r = 0; r < 4; r++) oacc[j][r] *= alpha[r];

    // P (C-layout) -> LDS (A-layout source); same-wave rows only, no barrier
#pragma unroll
    for (int t = 0; t < 4; t++)
#pragma unroll
      for (int r = 0; r < 4; r++)
        Ps[(wave*16 + q*4 + r)*FLD + t*16 + lm] = f2bf(sacc[t][r]);

    // O += P @ V
#pragma unroll
    for (int kk = 0; kk < 2; kk++) {
      short8 pf = *(const short8*)&Ps[(wave*16 + lm)*FLD + kk*32 + q*8];
#pragma unroll
      for (int j = 0; j < 4; j++) {
        short8 vf = *(const short8*)&Vts[(j*16 + lm)*FLD + kk*32 + q*8];
        oacc[j] = __builtin_amdgcn_mfma_f32_16x16x32_bf16(pf, vf, oacc[j], 0, 0, 0);
      }
    }
  }

  // epilogue: O /= l, store ctx bf16
  float inv[4];
#pragma unroll
  for (int r = 0; r < 4; r++) inv[r] = 1.0f / lrun[r];
#pragma unroll
  for (int j = 0; j < 4; j++)
#pragma unroll
    for (int r = 0; r < 4; r++) {
      int row = q0 + wave*16 + q*4 + r;
      if (row < SEQ)
        ctx[((long)(b*SEQ + row))*EMB + h*DKH + j*16 + lm] = f2bf(oacc[j][r] * inv[r]);
    }
}

extern "C" void kernel_launch(void* const* d_in, const int* in_sizes, int n_in,
                              void* d_out, int out_size, void* d_ws, size_t ws_size,
                              hipStream_t stream) {
  const float* x     = (const float*)d_in[0];
  const float* wq    = (const float*)d_in[1];
  const float* bq    = (const float*)d_in[2];
  const float* wk    = (const float*)d_in[3];
  const float* bk    = (const float*)d_in[4];
  const float* wv    = (const float*)d_in[5];
  const float* bv    = (const float*)d_in[6];
  const float* wo    = (const float*)d_in[7];
  const float* bo    = (const float*)d_in[8];
  const float* w1    = (const float*)d_in[9];
  const float* bf1   = (const float*)d_in[10];
  const float* w2    = (const float*)d_in[11];
  const float* bf2   = (const float*)d_in[12];
  const float* ln1g  = (const float*)d_in[13];
  const float* ln1b  = (const float*)d_in[14];
  const float* ln2g  = (const float*)d_in[15];
  const float* ln2b  = (const float*)d_in[16];
  float* out = (float*)d_out;

  char* w = (char*)d_ws;
  size_t off = 0;
  auto alloc = [&](size_t bytes) -> void* {
    void* p = w + off;
    off = (off + bytes + 255) & ~(size_t)255;
    return p;
  };
  unsigned short* WqkvT = (unsigned short*)alloc((size_t)3 * 768 * 768 * 2);
  unsigned short* WoT   = (unsigned short*)alloc((size_t)768 * 768 * 2);
  unsigned short* W1T   = (unsigned short*)alloc((size_t)3072 * 768 * 2);
  unsigned short* W2T   = (unsigned short*)alloc((size_t)768 * 3072 * 2);
  float*          bqkv  = (float*)alloc(2304 * 4);
  unsigned short* hbuf  = (unsigned short*)alloc((size_t)MTOK * EMB * 2);   // h1 / ctx / h2
  unsigned short* qkv   = (unsigned short*)alloc((size_t)MTOK * 3 * EMB * 2);
  unsigned short* vT    = (unsigned short*)alloc((size_t)BHN * DKH * VLD * 2);
  float*          x1    = (float*)alloc((size_t)MTOK * EMB * 4);
  unsigned short* g     = (unsigned short*)alloc((size_t)MTOK * DFF * 2);
  (void)ws_size; (void)in_sizes; (void)n_in; (void)out_size;

  dim3 blk(256);

  transpose_convert<<<dim3(24, 24), blk, 0, stream>>>(wq, WqkvT,               768, 768);
  transpose_convert<<<dim3(24, 24), blk, 0, stream>>>(wk, WqkvT + 768 * 768,   768, 768);
  transpose_convert<<<dim3(24, 24), blk, 0, stream>>>(wv, WqkvT + 2*768*768,   768, 768);
  transpose_convert<<<dim3(24, 24), blk, 0, stream>>>(wo, WoT,                 768, 768);
  transpose_convert<<<dim3(96, 24), blk, 0, stream>>>(w1, W1T,                 768, 3072);
  transpose_convert<<<dim3(24, 96), blk, 0, stream>>>(w2, W2T,                 3072, 768);
  concat_bias<<<dim3(9), blk, 0, stream>>>(bq, bk, bv, bqkv);

  ln_kernel<<<dim3(MTOK), blk, 0, stream>>>(x, ln1g, ln1b, hbuf);

  // QKV: [9232,768] @ [768,2304]
  gemm128<true, false, false, false><<<dim3(18, 73), blk, 0, stream>>>(
      hbuf, WqkvT, bqkv, nullptr, nullptr, qkv,
      MTOK, 3*EMB, EMB, EMB, EMB, 3*EMB);

  transpose_v<<<dim3(19, 2, BHN), blk, 0, stream>>>(qkv, vT);

  // fused attention -> ctx (hbuf)
  flash_attn<<<dim3(10, BHN), blk, 0, stream>>>(qkv, vT, hbuf);

  // O-proj + residual -> x1 (fp32)
  gemm128<true, true, false, true><<<dim3(6, 73), blk, 0, stream>>>(
      hbuf, WoT, bo, x, x1, nullptr,
      MTOK, EMB, EMB, EMB, EMB, EMB);

  ln_kernel<<<dim3(MTOK), blk, 0, stream>>>(x1, ln2g, ln2b, hbuf);

  // FFN1 + bias + exact GELU -> g (bf16)
  gemm128<true, false, true, false><<<dim3(24, 73), blk, 0, stream>>>(
      hbuf, W1T, bf1, nullptr, nullptr, g,
      MTOK, DFF, EMB, EMB, EMB, DFF);

  // FFN2 + bias + residual -> out (fp32)
  gemm128<true, true, false, true><<<dim3(6, 73), blk, 0, stream>>>(
      g, W2T, bf2, x1, out, nullptr,
      MTOK, EMB, DFF, DFF, DFF, EMB);
}

// Round 3
// 529.311 us; speedup vs baseline: 1.9495x; 1.0265x over previous
//
#include <hip/hip_runtime.h>
#include <hip/hip_bf16.h>
#include <math.h>

#define EMB 768
#define HEADS 12
#define DKH 64
#define DFF 3072
#define NB 16
#define SEQ 577
#define MTOK (NB*SEQ)      // 9232
#define BHN (NB*HEADS)     // 192
#define VLD 640            // vT row stride (bf16 elems)

typedef __attribute__((ext_vector_type(8))) short short8;
typedef __attribute__((ext_vector_type(4))) float f32x4;

__device__ __forceinline__ unsigned short f2bf(float f) {
  __hip_bfloat16 h = __float2bfloat16(f);
  return *reinterpret_cast<unsigned short*>(&h);
}

// fast GELU: x * sigmoid(2*0.79788456*(x + 0.044715 x^3)); |err| < ~1.5e-3
__device__ __forceinline__ float gelu_f(float x) {
  float u = x * (1.5957691216f + 0.0713548162726f * x * x);
  return x / (1.0f + __expf(-u));
}

__device__ __forceinline__ void gld_lds16(const unsigned short* g, unsigned short* l) {
  __builtin_amdgcn_global_load_lds(
      (const __attribute__((address_space(1))) unsigned int*)(g),
      (__attribute__((address_space(3))) unsigned int*)(l), 16, 0, 0);
}

// ---------------- LayerNorm: fp32 [row,768] -> bf16 [row,768] ----------------
__global__ __launch_bounds__(256) void ln_kernel(
    const float* __restrict__ x, const float* __restrict__ g,
    const float* __restrict__ b, unsigned short* __restrict__ out) {
  int row = blockIdx.x;
  int tid = threadIdx.x;
  const float* xr = x + (long)row * EMB;
  float v0 = xr[tid], v1 = xr[tid + 256], v2 = xr[tid + 512];
  float s = v0 + v1 + v2;
  float sq = v0*v0 + v1*v1 + v2*v2;
  for (int off = 32; off; off >>= 1) {
    s  += __shfl_down(s,  off, 64);
    sq += __shfl_down(sq, off, 64);
  }
  __shared__ float sh[8];
  int wid = tid >> 6, lane = tid & 63;
  if (lane == 0) { sh[wid] = s; sh[4 + wid] = sq; }
  __syncthreads();
  s  = sh[0] + sh[1] + sh[2] + sh[3];
  sq = sh[4] + sh[5] + sh[6] + sh[7];
  float mu = s * (1.0f / EMB);
  float var = sq * (1.0f / EMB) - mu * mu;
  float rs = rsqrtf(var + 1e-5f);
  unsigned short* orow = out + (long)row * EMB;
  orow[tid]       = f2bf((v0 - mu) * rs * g[tid]       + b[tid]);
  orow[tid + 256] = f2bf((v1 - mu) * rs * g[tid + 256] + b[tid + 256]);
  orow[tid + 512] = f2bf((v2 - mu) * rs * g[tid + 512] + b[tid + 512]);
}

// ------------- transpose+convert: fp32 src[R,C] -> bf16 dst[C,R] -------------
__global__ __launch_bounds__(256) void transpose_convert(
    const float* __restrict__ src, unsigned short* __restrict__ dst,
    int R, int C) {
  __shared__ float t[32][33];
  int tx = threadIdx.x & 31, ty = threadIdx.x >> 5;
  int r0 = blockIdx.y * 32, c0 = blockIdx.x * 32;
#pragma unroll
  for (int l = 0; l < 4; l++)
    t[ty + l*8][tx] = src[(long)(r0 + ty + l*8) * C + c0 + tx];
  __syncthreads();
#pragma unroll
  for (int l = 0; l < 4; l++)
    dst[(long)(c0 + ty + l*8) * R + r0 + tx] = f2bf(t[tx][ty + l*8]);
}

// ------------------- concat bq|bk|bv into one fp32[2304] ---------------------
__global__ void concat_bias(const float* __restrict__ a, const float* __restrict__ b,
                            const float* __restrict__ c, float* __restrict__ o) {
  int i = blockIdx.x * 256 + threadIdx.x;
  if (i < 768) o[i] = a[i];
  else if (i < 1536) o[i] = b[i - 768];
  else if (i < 2304) o[i] = c[i - 1536];
}

// --------- vT: qkv v-part [b,s,h,d] -> vT[bh][d][s] (row stride VLD) ---------
__global__ __launch_bounds__(256) void transpose_v(
    const unsigned short* __restrict__ qkv, unsigned short* __restrict__ vT) {
  __shared__ unsigned short t[32][33];
  int bhi = blockIdx.z;
  int b = bhi / HEADS, h = bhi % HEADS;
  int s0 = blockIdx.x * 32, d0 = blockIdx.y * 32;
  int tx = threadIdx.x & 31, ty = threadIdx.x >> 5;
  const unsigned short* base = qkv + ((long)b * SEQ) * (3*EMB) + 2*EMB + h*DKH;
#pragma unroll
  for (int l = 0; l < 4; l++) {
    int s = s0 + ty + l*8;
    t[ty + l*8][tx] = (s < SEQ) ? base[(long)s * (3*EMB) + d0 + tx] : (unsigned short)0;
  }
  __syncthreads();
  unsigned short* ob = vT + ((long)bhi * DKH) * VLD;
#pragma unroll
  for (int l = 0; l < 4; l++) {
    int d = d0 + ty + l*8;
    int s = s0 + tx;
    if (s < SEQ) ob[(long)d * VLD + s] = t[tx][ty + l*8];
  }
}

// ------- m97-structure GEMM: C[M,N] = A[M,K] @ Bt[N,K]^T, swizzled LDS -------
// Block tile 128 x BN, BK=32, global_load_lds w16, 4 waves.
// LDS slot (r, c8) holds global colgroup c8 ^ ((r>>1)&3)  -> 2-way banks (free).
template<bool BIAS, bool RESID, bool GELU_, bool OF32, int BN>
__global__ __launch_bounds__(256) void gemm128(
    const unsigned short* __restrict__ A,
    const unsigned short* __restrict__ Bt,
    const float* __restrict__ bias,
    const float* __restrict__ resid,
    float* __restrict__ outf,
    unsigned short* __restrict__ outb,
    int M, int N, int K, int lda, int ldb, int ldc) {
  constexpr int NT = BN / 32;              // n-subtiles (16-wide) per wave
  __shared__ unsigned short As[128 * 32];
  __shared__ unsigned short Bs[BN * 32];

  const int m0 = blockIdx.y * 128, n0 = blockIdx.x * BN;
  const int tid = threadIdx.x;
  const int wave = tid >> 6, lane = tid & 63;
  const int wm = (wave >> 1) * 64, wn = (wave & 1) * (BN / 2);
  const int lm = lane & 15, q = lane >> 4;
  const int qs = ((q ^ ((lm >> 1) & 3)) * 8);   // swizzled read col offset

  // staging: lane covers 16B; LDS offset 8*tid; global colgroup swizzled
  const int srow = tid >> 2;
  const int scol = (((tid & 3) ^ ((tid >> 3) & 3)) * 8);
  int gmA0 = m0 + srow;        if (gmA0 > M - 1) gmA0 = M - 1;
  int gmA1 = m0 + srow + 64;   if (gmA1 > M - 1) gmA1 = M - 1;
  const int gnB0 = n0 + srow, gnB1 = n0 + srow + 64;

  f32x4 acc[4][NT];
#pragma unroll
  for (int i = 0; i < 4; i++)
#pragma unroll
    for (int j = 0; j < NT; j++) acc[i][j] = (f32x4){0,0,0,0};

  for (int k0 = 0; k0 < K; k0 += 32) {
    gld_lds16(A  + (long)gmA0 * lda + k0 + scol, &As[8*tid]);
    gld_lds16(A  + (long)gmA1 * lda + k0 + scol, &As[8*tid + 2048]);
    gld_lds16(Bt + (long)gnB0 * ldb + k0 + scol, &Bs[8*tid]);
    if (BN == 128)
      gld_lds16(Bt + (long)gnB1 * ldb + k0 + scol, &Bs[8*tid + 2048]);
    asm volatile("s_waitcnt vmcnt(0)" ::: "memory");
    __syncthreads();

    short8 af[4], bf[NT];
#pragma unroll
    for (int i = 0; i < 4; i++) af[i] = *(const short8*)&As[(wm + i*16 + lm) * 32 + qs];
#pragma unroll
    for (int j = 0; j < NT; j++) bf[j] = *(const short8*)&Bs[(wn + j*16 + lm) * 32 + qs];
#pragma unroll
    for (int i = 0; i < 4; i++)
#pragma unroll
      for (int j = 0; j < NT; j++)
        acc[i][j] = __builtin_amdgcn_mfma_f32_16x16x32_bf16(af[i], bf[j], acc[i][j], 0, 0, 0);
    __syncthreads();
  }

#pragma unroll
  for (int i = 0; i < 4; i++) {
#pragma unroll
    for (int j = 0; j < NT; j++) {
      int col = n0 + wn + j*16 + lm;
      float bv = BIAS ? bias[col] : 0.0f;
#pragma unroll
      for (int r = 0; r < 4; r++) {
        int row = m0 + wm + i*16 + q*4 + r;
        if (row >= M) continue;
        float v = acc[i][j][r] + bv;
        if (RESID) v += resid[(long)row * ldc + col];
        if (GELU_) v = gelu_f(v);
        long o = (long)row * ldc + col;
        if (OF32) outf[o] = v;
        else      outb[o] = f2bf(v);
      }
    }
  }
}

// ------------------ fused flash attention (unscaled scores) ------------------
#define FLD 72
__global__ __launch_bounds__(256) void flash_attn(
    const unsigned short* __restrict__ qkv,   // [MTOK][2304], q|k|v
    const unsigned short* __restrict__ vT,    // [bh][64][VLD]
    unsigned short* __restrict__ ctx) {       // [MTOK][768]
  __shared__ unsigned short Qs[64 * FLD];
  __shared__ unsigned short Ks[64 * FLD];
  __shared__ unsigned short Vts[64 * FLD];
  __shared__ unsigned short Ps[64 * FLD];

  const int q0 = blockIdx.x * 64;
  const int bh = blockIdx.y;
  const int b = bh / HEADS, h = bh % HEADS;
  const int tid = threadIdx.x;
  const int wave = tid >> 6, lane = tid & 63;
  const int lm = lane & 15, q = lane >> 4;

  const int sr = tid >> 3;
  const int sc = (tid & 7) * 8;

#pragma unroll
  for (int it = 0; it < 2; it++) {
    int r = sr + it*32;
    int s = q0 + r; if (s > SEQ - 1) s = SEQ - 1;
    *(uint4*)&Qs[r*FLD + sc] =
        *(const uint4*)(qkv + ((long)(b*SEQ + s))*(3*EMB) + h*DKH + sc);
  }
  __syncthreads();
  short8 qf0 = *(const short8*)&Qs[(wave*16 + lm)*FLD + q*8];
  short8 qf1 = *(const short8*)&Qs[(wave*16 + lm)*FLD + 32 + q*8];

  f32x4 oacc[4];
#pragma unroll
  for (int j = 0; j < 4; j++) oacc[j] = (f32x4){0,0,0,0};
  float mrun[4] = {-1e30f, -1e30f, -1e30f, -1e30f};
  float lrun[4] = {0.f, 0.f, 0.f, 0.f};

  for (int kt = 0; kt < 10; kt++) {
    __syncthreads();
#pragma unroll
    for (int it = 0; it < 2; it++) {
      int r = sr + it*32;
      int s = kt*64 + r; if (s > SEQ - 1) s = SEQ - 1;
      *(uint4*)&Ks[r*FLD + sc] =
          *(const uint4*)(qkv + ((long)(b*SEQ + s))*(3*EMB) + EMB + h*DKH + sc);
      *(uint4*)&Vts[r*FLD + sc] =
          *(const uint4*)(vT + ((long)bh*DKH + r)*VLD + kt*64 + sc);
    }
    __syncthreads();

    f32x4 sacc[4];
#pragma unroll
    for (int t = 0; t < 4; t++) {
      short8 kf0 = *(const short8*)&Ks[(t*16 + lm)*FLD + q*8];
      short8 kf1 = *(const short8*)&Ks[(t*16 + lm)*FLD + 32 + q*8];
      sacc[t] = __builtin_amdgcn_mfma_f32_16x16x32_bf16(qf0, kf0, (f32x4){0,0,0,0}, 0, 0, 0);
      sacc[t] = __builtin_amdgcn_mfma_f32_16x16x32_bf16(qf1, kf1, sacc[t], 0, 0, 0);
      int key = kt*64 + t*16 + lm;
      if (key >= SEQ) sacc[t] = (f32x4){-1e30f, -1e30f, -1e30f, -1e30f};
    }

    float mt[4];
#pragma unroll
    for (int r = 0; r < 4; r++)
      mt[r] = fmaxf(fmaxf(sacc[0][r], sacc[1][r]), fmaxf(sacc[2][r], sacc[3][r]));
#pragma unroll
    for (int d = 1; d <= 8; d <<= 1)
#pragma unroll
      for (int r = 0; r < 4; r++) mt[r] = fmaxf(mt[r], __shfl_xor(mt[r], d, 64));

    float alpha[4], rs[4];
#pragma unroll
    for (int r = 0; r < 4; r++) {
      float mnew = fmaxf(mrun[r], mt[r]);
      alpha[r] = __expf(mrun[r] - mnew);
      mrun[r] = mnew;
      rs[r] = 0.f;
    }
#pragma unroll
    for (int t = 0; t < 4; t++)
#pragma unroll
      for (int r = 0; r < 4; r++) {
        float p = __expf(sacc[t][r] - mrun[r]);
        sacc[t][r] = p;
        rs[r] += p;
      }
#pragma unroll
    for (int d = 1; d <= 8; d <<= 1)
#pragma unroll
      for (int r = 0; r < 4; r++) rs[r] += __shfl_xor(rs[r], d, 64);
#pragma unroll
    for (int r = 0; r < 4; r++) lrun[r] = alpha[r]*lrun[r] + rs[r];
#pragma unroll
    for (int j = 0; j < 4; j++)
#pragma unroll
      for (int r = 0; r < 4; r++) oacc[j][r] *= alpha[r];

#pragma unroll
    for (int t = 0; t < 4; t++)
#pragma unroll
      for (int r = 0; r < 4; r++)
        Ps[(wave*16 + q*4 + r)*FLD + t*16 + lm] = f2bf(sacc[t][r]);

#pragma unroll
    for (int kk = 0; kk < 2; kk++) {
      short8 pf = *(const short8*)&Ps[(wave*16 + lm)*FLD + kk*32 + q*8];
#pragma unroll
      for (int j = 0; j < 4; j++) {
        short8 vf = *(const short8*)&Vts[(j*16 + lm)*FLD + kk*32 + q*8];
        oacc[j] = __builtin_amdgcn_mfma_f32_16x16x32_bf16(pf, vf, oacc[j], 0, 0, 0);
      }
    }
  }

  float inv[4];
#pragma unroll
  for (int r = 0; r < 4; r++) inv[r] = 1.0f / lrun[r];
#pragma unroll
  for (int j = 0; j < 4; j++)
#pragma unroll
    for (int r = 0; r < 4; r++) {
      int row = q0 + wave*16 + q*4 + r;
      if (row < SEQ)
        ctx[((long)(b*SEQ + row))*EMB + h*DKH + j*16 + lm] = f2bf(oacc[j][r] * inv[r]);
    }
}

extern "C" void kernel_launch(void* const* d_in, const int* in_sizes, int n_in,
                              void* d_out, int out_size, void* d_ws, size_t ws_size,
                              hipStream_t stream) {
  const float* x     = (const float*)d_in[0];
  const float* wq    = (const float*)d_in[1];
  const float* bq    = (const float*)d_in[2];
  const float* wk    = (const float*)d_in[3];
  const float* bk    = (const float*)d_in[4];
  const float* wv    = (const float*)d_in[5];
  const float* bv    = (const float*)d_in[6];
  const float* wo    = (const float*)d_in[7];
  const float* bo    = (const float*)d_in[8];
  const float* w1    = (const float*)d_in[9];
  const float* bf1   = (const float*)d_in[10];
  const float* w2    = (const float*)d_in[11];
  const float* bf2   = (const float*)d_in[12];
  const float* ln1g  = (const float*)d_in[13];
  const float* ln1b  = (const float*)d_in[14];
  const float* ln2g  = (const float*)d_in[15];
  const float* ln2b  = (const float*)d_in[16];
  float* out = (float*)d_out;

  char* w = (char*)d_ws;
  size_t off = 0;
  auto alloc = [&](size_t bytes) -> void* {
    void* p = w + off;
    off = (off + bytes + 255) & ~(size_t)255;
    return p;
  };
  unsigned short* WqkvT = (unsigned short*)alloc((size_t)3 * 768 * 768 * 2);
  unsigned short* WoT   = (unsigned short*)alloc((size_t)768 * 768 * 2);
  unsigned short* W1T   = (unsigned short*)alloc((size_t)3072 * 768 * 2);
  unsigned short* W2T   = (unsigned short*)alloc((size_t)768 * 3072 * 2);
  float*          bqkv  = (float*)alloc(2304 * 4);
  unsigned short* hbuf  = (unsigned short*)alloc((size_t)MTOK * EMB * 2);
  unsigned short* qkv   = (unsigned short*)alloc((size_t)MTOK * 3 * EMB * 2);
  unsigned short* vT    = (unsigned short*)alloc((size_t)BHN * DKH * VLD * 2);
  float*          x1    = (float*)alloc((size_t)MTOK * EMB * 4);
  unsigned short* g     = (unsigned short*)alloc((size_t)MTOK * DFF * 2);
  (void)ws_size; (void)in_sizes; (void)n_in; (void)out_size;

  dim3 blk(256);

  transpose_convert<<<dim3(24, 24), blk, 0, stream>>>(wq, WqkvT,               768, 768);
  transpose_convert<<<dim3(24, 24), blk, 0, stream>>>(wk, WqkvT + 768 * 768,   768, 768);
  transpose_convert<<<dim3(24, 24), blk, 0, stream>>>(wv, WqkvT + 2*768*768,   768, 768);
  transpose_convert<<<dim3(24, 24), blk, 0, stream>>>(wo, WoT,                 768, 768);
  transpose_convert<<<dim3(96, 24), blk, 0, stream>>>(w1, W1T,                 768, 3072);
  transpose_convert<<<dim3(24, 96), blk, 0, stream>>>(w2, W2T,                 3072, 768);
  concat_bias<<<dim3(9), blk, 0, stream>>>(bq, bk, bv, bqkv);

  ln_kernel<<<dim3(MTOK), blk, 0, stream>>>(x, ln1g, ln1b, hbuf);

  // QKV: [9232,768] @ [768,2304]
  gemm128<true, false, false, false, 128><<<dim3(18, 73), blk, 0, stream>>>(
      hbuf, WqkvT, bqkv, nullptr, nullptr, qkv,
      MTOK, 3*EMB, EMB, EMB, EMB, 3*EMB);

  transpose_v<<<dim3(19, 2, BHN), blk, 0, stream>>>(qkv, vT);

  // fused attention -> ctx (hbuf)
  flash_attn<<<dim3(10, BHN), blk, 0, stream>>>(qkv, vT, hbuf);

  // O-proj + residual -> x1 (fp32); BN=64 for occupancy (N=768)
  gemm128<true, true, false, true, 64><<<dim3(12, 73), blk, 0, stream>>>(
      hbuf, WoT, bo, x, x1, nullptr,
      MTOK, EMB, EMB, EMB, EMB, EMB);

  ln_kernel<<<dim3(MTOK), blk, 0, stream>>>(x1, ln2g, ln2b, hbuf);

  // FFN1 + bias + fast GELU -> g (bf16)
  gemm128<true, false, true, false, 128><<<dim3(24, 73), blk, 0, stream>>>(
      hbuf, W1T, bf1, nullptr, nullptr, g,
      MTOK, DFF, EMB, EMB, EMB, DFF);

  // FFN2 + bias + residual -> out (fp32); BN=64 (N=768)
  gemm128<true, true, false, true, 64><<<dim3(12, 73), blk, 0, stream>>>(
      g, W2T, bf2, x1, out, nullptr,
      MTOK, EMB, DFF, DFF, DFF, EMB);
}